// Round 4
// baseline (189.460 us; speedup 1.0000x reference)
//
#include <hip/hip_runtime.h>

#define SDIM 500
#define DDIM 64

__device__ __forceinline__ unsigned ford(float x) {
    unsigned u = __float_as_uint(x);
    return u ^ ((unsigned)((int)u >> 31) | 0x80000000u);
}

__device__ __forceinline__ float dot16(float4 a0, float4 a1, float4 a2, float4 a3,
                                       float4 b0, float4 b1, float4 b2, float4 b3) {
    return a0.x*b0.x + a0.y*b0.y + a0.z*b0.z + a0.w*b0.w
         + a1.x*b1.x + a1.y*b1.y + a1.z*b1.z + a1.w*b1.w
         + a2.x*b2.x + a2.y*b2.y + a2.z*b2.z + a2.w*b2.w
         + a3.x*b3.x + a3.y*b3.y + a3.z*b3.z + a3.w*b3.w;
}

// One wave (64 threads) per row. No inter-wave coupling: __syncthreads in a
// single-wave workgroup is a near-free waitcnt (compiler knows blockDim=64).
__global__ __launch_bounds__(64) void rs_main(
    const int* __restrict__ need_replace,    // (N,2)
    const float* __restrict__ union_feature, // (N,128)
    const float* __restrict__ all_items,     // (n_items,64)
    const int* __restrict__ sample_items,    // (n_users,500)
    const float* __restrict__ Wm,            // (64,128)
    const float* __restrict__ bv,            // (64)
    const float* __restrict__ gumbel_u,      // (N,500)
    float* __restrict__ out_items,           // (N)
    float* __restrict__ out_feat,            // (N,64)
    int* __restrict__ ws_acc)                // [0]=sum(pos), [1]=sum|pos-250|
{
    __shared__ unsigned s_fv[SDIM];
    __shared__ int s_hist[256];
    __shared__ __align__(16) float s_uif[DDIM];

    const int n    = blockIdx.x;
    const int lane = threadIdx.x;
    const int part = lane & 3, quad = lane >> 2;

    const int user = need_replace[2 * n];
    const int item = need_replace[2 * n + 1];
    const int*   samp = sample_items + (long)user * SDIM;
    const float* gur  = gumbel_u + (long)n * SDIM;

    // item-embedding fragment: 16 floats per lane, selected by part
    const float4* ir = (const float4*)(all_items + (long)item * DDIM) + part * 4;
    const float4 wiA = ir[0], wiB = ir[1], wiC = ir[2], wiD = ir[3];

    // ---- uif = W @ uf + b : quad q computes rows q, q+16, q+32, q+48 ----
    {
        const float4* ufr = (const float4*)(union_feature + (long)n * 128) + part * 8;
        float4 u0 = ufr[0], u1 = ufr[1], u2 = ufr[2], u3 = ufr[3];
        float4 u4 = ufr[4], u5 = ufr[5], u6 = ufr[6], u7 = ufr[7];
        #pragma unroll
        for (int r = 0; r < 4; ++r) {
            const int row = quad + 16 * r;
            const float4* wr = (const float4*)(Wm + (long)row * 128) + part * 8;
            float4 w0 = wr[0], w1 = wr[1], w2 = wr[2], w3 = wr[3];
            float4 w4 = wr[4], w5 = wr[5], w6 = wr[6], w7 = wr[7];
            float acc = dot16(w0, w1, w2, w3, u0, u1, u2, u3)
                      + dot16(w4, w5, w6, w7, u4, u5, u6, u7);
            acc += __shfl_xor(acc, 1);
            acc += __shfl_xor(acc, 2);
            if (part == 0) s_uif[row] = acc + bv[row];
        }
    }
    __syncthreads();
    const float4* ur = (const float4*)s_uif + part * 4;
    const float4 wuA = ur[0], wuB = ur[1], wuC = ur[2], wuD = ur[3];

    // ---- score phase: quad per sample row, fused gumbel + argmax ----
    float bvv = -__builtin_inff();
    int   bii = SDIM;
    #pragma unroll 4
    for (int i = 0; i < 32; ++i) {
        const int s = i * 16 + quad;
        const bool act = (s < SDIM);
        const int sc = act ? s : 0;
        const int idx = samp[sc];
        const float4* fr = (const float4*)(all_items + (long)idx * DDIM) + part * 4;
        float4 f0 = fr[0], f1 = fr[1], f2 = fr[2], f3 = fr[3];
        float a0 = dot16(f0, f1, f2, f3, wiA, wiB, wiC, wiD);
        float a1 = dot16(f0, f1, f2, f3, wuA, wuB, wuC, wuD);
        a0 += __shfl_xor(a0, 1); a0 += __shfl_xor(a0, 2);
        a1 += __shfl_xor(a1, 1); a1 += __shfl_xor(a1, 2);
        float u = gur[sc];
        float g = -logf(-logf(u * (1.0f - 2e-7f) + 1e-7f));
        float v = a1 + g;
        if (act) {
            if (v > bvv) { bvv = v; bii = s; }   // ascending s keeps first max
            if (part == 0) s_fv[s] = ford(a0);
        }
    }
    // wave argmax, first-index tie-break (matches jnp.argmax)
    #pragma unroll
    for (int off = 1; off < 64; off <<= 1) {
        float v2 = __shfl_xor(bvv, off);
        int   i2 = __shfl_xor(bii, off);
        if (v2 > bvv || (v2 == bvv && i2 < bii)) { bvv = v2; bii = i2; }
    }
    const int k = bii;
    __syncthreads();

    // ---- rank_k = stable rank of element k ----
    int rank_k = 0;
    {
        const unsigned fvk = s_fv[k];
        for (int s = lane; s < SDIM; s += 64) {
            unsigned v = s_fv[s];
            rank_k += (int)((v < fvk) | ((v == fvk) & (s < k)));
        }
        #pragma unroll
        for (int off = 1; off < 64; off <<= 1) rank_k += __shfl_xor(rank_k, off);
    }

    // ---- radix-select: j* = index of k-th smallest (stable) ----
    unsigned prefix = 0;
    int krem = k;
    #pragma unroll
    for (int pass = 0; pass < 4; ++pass) {
        const int shift = 24 - 8 * pass;
        s_hist[lane] = 0; s_hist[lane + 64] = 0; s_hist[lane + 128] = 0; s_hist[lane + 192] = 0;
        __syncthreads();
        const unsigned himask = pass ? (0xFFFFFFFFu << (shift + 8)) : 0u;
        for (int s = lane; s < SDIM; s += 64) {
            unsigned v = s_fv[s];
            if ((v & himask) == prefix) atomicAdd(&s_hist[(v >> shift) & 0xFF], 1);
        }
        __syncthreads();
        int h0 = s_hist[4 * lane], h1 = s_hist[4 * lane + 1];
        int h2 = s_hist[4 * lane + 2], h3 = s_hist[4 * lane + 3];
        int s4 = h0 + h1 + h2 + h3, inc = s4;
        #pragma unroll
        for (int off = 1; off < 64; off <<= 1) {
            int t = __shfl_up(inc, off);
            if (lane >= off) inc += t;
        }
        const int base = inc - s4;
        const bool found = (krem >= base) && (krem < inc);
        int selb = 0, selk = 0;
        if (found) {
            if      (krem < base + h0)           { selb = 4 * lane;     selk = krem - base; }
            else if (krem < base + h0 + h1)      { selb = 4 * lane + 1; selk = krem - base - h0; }
            else if (krem < base + h0 + h1 + h2) { selb = 4 * lane + 2; selk = krem - base - h0 - h1; }
            else                                 { selb = 4 * lane + 3; selk = krem - base - h0 - h1 - h2; }
        }
        unsigned long long m = __ballot(found);
        int srcl = __ffsll((long long)m) - 1;
        selb = __shfl(selb, srcl);
        selk = __shfl(selk, srcl);
        prefix |= ((unsigned)selb) << shift;
        krem = selk;
        __syncthreads();
    }

    // ---- stable tie resolution among fv==prefix by original index ----
    int jstar = -1;
    {
        int basec = 0;
        #pragma unroll
        for (int c = 0; c < 8; ++c) {
            const int s = c * 64 + lane;
            const bool m = (s < SDIM) && (s_fv[s] == prefix);
            unsigned long long mask = __ballot(m);
            int myrank = __popcll(mask & ((1ull << lane) - 1ull));
            if (m && (basec + myrank == krem)) jstar = s;
            basec += __popcll(mask);
        }
        unsigned long long mm = __ballot(jstar >= 0);
        int srcl = __ffsll((long long)mm) - 1;
        jstar = __shfl(jstar, srcl);
    }

    // ---- outputs ----
    const int src_item = samp[k];
    out_feat[(long)n * DDIM + lane] = all_items[(long)src_item * DDIM + lane];
    if (lane == 0) {
        out_items[n] = (float)samp[jstar];
        const int pos = rank_k + 1;                 // similarity = pos/500
        atomicAdd(&ws_acc[0], pos);                 // for mean(similarity)
        atomicAdd(&ws_acc[1], abs(pos - 250));      // |sim-0.5| = |pos-250|/500
    }
}

__global__ __launch_bounds__(64) void rs_fin(const int* __restrict__ ws_acc,
                                             float* __restrict__ out_scal, int N)
{
    if (threadIdx.x == 0) {
        const double denom = (double)SDIM * (double)N;
        out_scal[0] = (float)((double)ws_acc[1] / denom);  // similarity_loss
        out_scal[1] = (float)((double)ws_acc[0] / denom);  // mean(similarity)
    }
}

extern "C" void kernel_launch(void* const* d_in, const int* in_sizes, int n_in,
                              void* d_out, int out_size, void* d_ws, size_t ws_size,
                              hipStream_t stream) {
    const int*   need_replace  = (const int*)d_in[0];
    const float* union_feature = (const float*)d_in[1];
    const float* all_items     = (const float*)d_in[2];
    const int*   sample_items  = (const int*)d_in[3];
    const float* Wm            = (const float*)d_in[4];
    const float* bv            = (const float*)d_in[5];
    const float* gumbel_u      = (const float*)d_in[6];

    const int N = in_sizes[0] / 2;  // 4096

    float* out       = (float*)d_out;
    float* out_items = out;                       // N
    float* out_feat  = out + N;                   // N*64
    float* out_scal  = out + N + (long)N * DDIM;  // 2 scalars
    int*   ws_acc    = (int*)d_ws;                // 2 ints

    hipMemsetAsync(ws_acc, 0, 2 * sizeof(int), stream);
    rs_main<<<N, 64, 0, stream>>>(need_replace, union_feature, all_items,
                                  sample_items, Wm, bv, gumbel_u,
                                  out_items, out_feat, ws_acc);
    rs_fin<<<1, 64, 0, stream>>>(ws_acc, out_scal, N);
}